// Round 1
// baseline (207.057 us; speedup 1.0000x reference)
//
#include <hip/hip_runtime.h>
#include <stdint.h>

typedef __attribute__((ext_vector_type(8))) short short8;
typedef __attribute__((ext_vector_type(4))) float f32x4;

// fp32 -> bf16 round-to-nearest-even, returned in low 16 bits
static __device__ __forceinline__ uint32_t f2bf1(float f) {
    union { float f; uint32_t u; } v; v.f = f;
    return (v.u + 0x7FFFu + ((v.u >> 16) & 1u)) >> 16;
}

// XOR-swizzle on 16B granules within an 8KB buffer: inject row bits into bank bits.
// Bijective involution (bits 4-6 of granule index XORed into bits 0-2).
static __device__ __forceinline__ int swz(int byteoff) {
    int g = byteoff >> 4;
    g ^= (g >> 4) & 7;
    return (g << 4) | (byteoff & 15);
}

__global__ __launch_bounds__(256, 2) void bl_kernel(
    const float* __restrict__ x, const float* __restrict__ w1,
    const float* __restrict__ w2, float* __restrict__ out, int ntok)
{
    __shared__ __align__(16) uint8_t xlds[8192];   // X tile, [32][128] bf16, swizzled
    __shared__ __align__(16) uint8_t a2lds[8192];  // permuted intermediate, same layout

    const int tid  = threadIdx.x;
    const int wid  = tid >> 6;    // wave 0..3 -> owns output cols [wid*32, wid*32+32)
    const int lane = tid & 63;
    const int lrow = lane & 15;   // MFMA fragment row/col index
    const int lgrp = lane >> 4;   // MFMA k-octet group

    // ---- Load W1/W2 B-fragments into registers (held for whole kernel) ----
    // B-frag for 16x16x32: n = lane&15, k = 8*(lane>>4)+i ; frag (nt, ks) covers
    // cols [ (wid*2+nt)*16 , +16 ), k rows [ks*32, ks*32+32)
    short8 wf0[2][4], wf1[2][4];
#pragma unroll
    for (int nt = 0; nt < 2; ++nt) {
        const int col = (wid * 2 + nt) * 16 + lrow;
#pragma unroll
        for (int ks = 0; ks < 4; ++ks) {
            short8 f0, f1;
#pragma unroll
            for (int i = 0; i < 8; ++i) {
                const int rowk = ks * 32 + lgrp * 8 + i;
                f0[i] = (short)f2bf1(w1[rowk * 128 + col]);
                f1[i] = (short)f2bf1(w2[rowk * 128 + col]);
            }
            wf0[nt][ks] = f0;
            wf1[nt][ks] = f1;
        }
    }

    const int stride = gridDim.x;
    float4 xr[4];
    const int t0 = blockIdx.x;
    if (t0 < ntok) {
        const float4* p = (const float4*)(x + (size_t)t0 * 4096);
#pragma unroll
        for (int k = 0; k < 4; ++k) xr[k] = p[tid + 256 * k];
    }

    for (int t = t0; t < ntok; t += stride) {
        // ---- stage current token to LDS (bf16), prefetch next token ----
        uint2 pk[4];
#pragma unroll
        for (int k = 0; k < 4; ++k) {
            pk[k].x = f2bf1(xr[k].x) | (f2bf1(xr[k].y) << 16);
            pk[k].y = f2bf1(xr[k].z) | (f2bf1(xr[k].w) << 16);
        }
        const int tn = t + stride;
        if (tn < ntok) {
            const float4* p = (const float4*)(x + (size_t)tn * 4096);
#pragma unroll
            for (int k = 0; k < 4; ++k) xr[k] = p[tid + 256 * k];
        }
        // thread holds floats at flat idx 4*tid + 1024*k -> bf16 bytes at 8*tid + 2048*k
#pragma unroll
        for (int k = 0; k < 4; ++k) {
            *(uint2*)(xlds + swz(8 * tid + 2048 * k)) = pk[k];
        }
        __syncthreads();  // B0: xlds ready; prev iter's a2lds reads done

        // ---- step 1: C1 = X * W1 (this wave: cols [wid*32, +32)) ----
        short8 af[2][4];
#pragma unroll
        for (int mt = 0; mt < 2; ++mt)
#pragma unroll
            for (int ks = 0; ks < 4; ++ks)
                af[mt][ks] = *(const short8*)(xlds +
                    swz(((mt * 16 + lrow) * 128 + ks * 32 + lgrp * 8) * 2));

        f32x4 acc[2][2];
#pragma unroll
        for (int mt = 0; mt < 2; ++mt)
#pragma unroll
            for (int nt = 0; nt < 2; ++nt)
                acc[mt][nt] = (f32x4){0.f, 0.f, 0.f, 0.f};
#pragma unroll
        for (int ks = 0; ks < 4; ++ks)
#pragma unroll
            for (int mt = 0; mt < 2; ++mt)
#pragma unroll
                for (int nt = 0; nt < 2; ++nt)
                    acc[mt][nt] = __builtin_amdgcn_mfma_f32_16x16x32_bf16(
                        af[mt][ks], wf0[nt][ks], acc[mt][nt], 0, 0, 0);

        // ---- permutation scatter: C1[r][n] -> flat[n*32 + r] (bf16 into a2lds) ----
        // lane's 4 regs are consecutive r at fixed n -> one ds_write_b64
#pragma unroll
        for (int mt = 0; mt < 2; ++mt)
#pragma unroll
            for (int nt = 0; nt < 2; ++nt) {
                const int n  = (wid * 2 + nt) * 16 + lrow;
                const int r0 = mt * 16 + lgrp * 4;
                uint2 v;
                v.x = f2bf1(acc[mt][nt][0]) | (f2bf1(acc[mt][nt][1]) << 16);
                v.y = f2bf1(acc[mt][nt][2]) | (f2bf1(acc[mt][nt][3]) << 16);
                *(uint2*)(a2lds + swz((n * 32 + r0) * 2)) = v;
            }
        __syncthreads();  // B1: a2lds ready; xlds reads done

        // ---- step 2: C2 = A2 * W2 ----
#pragma unroll
        for (int mt = 0; mt < 2; ++mt)
#pragma unroll
            for (int ks = 0; ks < 4; ++ks)
                af[mt][ks] = *(const short8*)(a2lds +
                    swz(((mt * 16 + lrow) * 128 + ks * 32 + lgrp * 8) * 2));

        f32x4 acc2[2][2];
#pragma unroll
        for (int mt = 0; mt < 2; ++mt)
#pragma unroll
            for (int nt = 0; nt < 2; ++nt)
                acc2[mt][nt] = (f32x4){0.f, 0.f, 0.f, 0.f};
#pragma unroll
        for (int ks = 0; ks < 4; ++ks)
#pragma unroll
            for (int mt = 0; mt < 2; ++mt)
#pragma unroll
                for (int nt = 0; nt < 2; ++nt)
                    acc2[mt][nt] = __builtin_amdgcn_mfma_f32_16x16x32_bf16(
                        af[mt][ks], wf1[nt][ks], acc2[mt][nt], 0, 0, 0);

        // ---- final permuted store: out[t*4096 + n*32 + r] = C2[r][n] (fp32) ----
        float* op = out + (size_t)t * 4096;
#pragma unroll
        for (int mt = 0; mt < 2; ++mt)
#pragma unroll
            for (int nt = 0; nt < 2; ++nt) {
                const int n  = (wid * 2 + nt) * 16 + lrow;
                const int r0 = mt * 16 + lgrp * 4;
                float4 o = make_float4(acc2[mt][nt][0], acc2[mt][nt][1],
                                       acc2[mt][nt][2], acc2[mt][nt][3]);
                *(float4*)(op + n * 32 + r0) = o;
            }
        // no barrier needed here: next iter's B0 orders a2lds reads vs writes,
        // and B1 already ordered xlds reads vs next iter's xlds writes.
    }
}

extern "C" void kernel_launch(void* const* d_in, const int* in_sizes, int n_in,
                              void* d_out, int out_size, void* d_ws, size_t ws_size,
                              hipStream_t stream) {
    const float* x  = (const float*)d_in[0];
    const float* w1 = (const float*)d_in[1];
    const float* w2 = (const float*)d_in[2];
    float* out = (float*)d_out;
    const int ntok = in_sizes[0] / 4096;  // 32768 for the bench shape
    const int nwg = 2048;
    hipLaunchKernelGGL(bl_kernel, dim3(nwg), dim3(256), 0, stream,
                       x, w1, w2, out, ntok);
}